// Round 2
// baseline (551.294 us; speedup 1.0000x reference)
//
#include <hip/hip_runtime.h>
#include <math.h>

// BoxDecoder: decode anchors + loc_preds into corner boxes, expand over C
// classes, emit [rows,6] box tensor + mask + batch_index (all as float32,
// concatenated flat in d_out).
//
// Layout: rows = B*A*C, row = (b*A + a)*C + c = t*C + c with t = b*A + a.
//   box_tensor[row] = {x1, y1, x2, y2, score, label=c+1}
//   mask[row]       = score >= thresh ? 1 : 0
//   batch_index[row]= b
//
// One thread per float2 of the box tensor (3 float2 per row). rem==2 thread
// also writes mask/batch_index for its row (consecutive rows -> coalesced).
//
// Magic divides use shift 2^38 (NOT 2^44 — R0 bug: row*invC overflowed u64).
// Exactness: m=floor(2^38/d)+1 correct for n < 2^38/d. C=8 -> n<2^35 (row
// max 2^24 ok); A=1e5 -> n<2.75e6 (t max 1.6e6 ok). Products stay < 2^59.

#define MAGIC_SHIFT 38

__global__ __launch_bounds__(256) void box_decode_kernel(
    const float4* __restrict__ anchors,   // [A] (cx, cy, w, h)
    const float4* __restrict__ loc,       // [B*A]
    const float*  __restrict__ cls,       // [B*A*C]
    const float*  __restrict__ varx_p,
    const float*  __restrict__ vary_p,
    const float*  __restrict__ th_p,
    float2*       __restrict__ out_box2,  // [rows*3]
    float*        __restrict__ out_mask,  // [rows]
    float*        __restrict__ out_bidx,  // [rows]
    unsigned n2,                          // rows*3
    unsigned A, unsigned C,
    unsigned long long invA,              // floor(2^38/A)+1
    unsigned long long invC)              // floor(2^38/C)+1
{
    unsigned j = blockIdx.x * 256u + threadIdx.x;
    if (j >= n2) return;

    unsigned row = j / 3u;                 // compile-time const div -> magic mul
    unsigned rem = j - row * 3u;

    // row = t*C + c ; t = b*A + a
    unsigned t = (unsigned)(((unsigned long long)row * invC) >> MAGIC_SHIFT);
    unsigned c = row - t * C;
    unsigned b = (unsigned)(((unsigned long long)t * invA) >> MAGIC_SHIFT);
    unsigned a = t - b * A;

    float varx = *varx_p;
    float vary = *vary_p;
    float th   = *th_p;

    float4 anc = anchors[a];   // cx, cy, aw, ah
    float4 lp  = loc[t];

    // xy = loc[:2]*varx*anchor_wh + anchor_xy ; wh = exp(loc[2:]*vary)*anchor_wh
    float x = fmaf(lp.x * varx, anc.z, anc.x);
    float y = fmaf(lp.y * varx, anc.w, anc.y);
    float w = expf(lp.z * vary) * anc.z;
    float h = expf(lp.w * vary) * anc.w;

    float score = cls[row];

    float2 r;
    if (rem == 0) {
        r.x = fmaf(w, -0.5f, x);
        r.y = fmaf(h, -0.5f, y);
    } else if (rem == 1) {
        r.x = fmaf(w, 0.5f, x);
        r.y = fmaf(h, 0.5f, y);
    } else {
        r.x = score;
        r.y = (float)(c + 1u);
    }
    out_box2[j] = r;

    if (rem == 2) {
        out_mask[row] = (score >= th) ? 1.0f : 0.0f;
        out_bidx[row] = (float)b;
    }
}

extern "C" void kernel_launch(void* const* d_in, const int* in_sizes, int n_in,
                              void* d_out, int out_size, void* d_ws, size_t ws_size,
                              hipStream_t stream) {
    const float* anchors = (const float*)d_in[0];
    const float* loc     = (const float*)d_in[1];
    const float* cls     = (const float*)d_in[2];
    const float* varx_p  = (const float*)d_in[3];
    const float* vary_p  = (const float*)d_in[4];
    const float* th_p    = (const float*)d_in[5];
    // d_in[6] = batch_size (not needed for the returned tensors)

    unsigned A = (unsigned)(in_sizes[0] / 4);
    unsigned B = (unsigned)((unsigned)in_sizes[1] / (4u * A));
    unsigned C = (unsigned)((unsigned)in_sizes[2] / (A * B));
    unsigned rows = B * A * C;
    unsigned n2 = rows * 3u;

    float* out_box  = (float*)d_out;
    float* out_mask = out_box + (size_t)rows * 6;
    float* out_bidx = out_mask + rows;

    unsigned long long invA = ((1ULL << MAGIC_SHIFT) / A) + 1ULL;
    unsigned long long invC = ((1ULL << MAGIC_SHIFT) / C) + 1ULL;

    dim3 grid((n2 + 255u) / 256u);
    box_decode_kernel<<<grid, dim3(256), 0, stream>>>(
        (const float4*)anchors, (const float4*)loc, cls,
        varx_p, vary_p, th_p,
        (float2*)out_box, out_mask, out_bidx,
        n2, A, C, invA, invC);
}

// Round 3
// 523.219 us; speedup vs baseline: 1.0537x; 1.0537x over previous
//
#include <hip/hip_runtime.h>
#include <math.h>

// BoxDecoder R3: float4-granular output, decode-once-per-anchor.
//
// Output layout (all float32, flat in d_out):
//   box_tensor [rows,6], rows = B*A*C; then mask [rows]; then batch_index [rows].
//   row = t*C + c, t = b*A + a. box repeats across c within a t (coords depend
//   only on t). 6*C floats per t = 48 floats = 12 float4 (requires (6*C)%4==0;
//   true for C=8).
//
// Box part: one thread per output float4 g. t = g/12 (magic), j = g%12,
// s = j/3, jm = j%3. Decode t once (2 expf), then:
//   jm==0 -> (x1,y1,x2,y2)                       [row 8t+2s box]
//   jm==1 -> (score[8t+2s],   2s+1, x1, y1)
//   jm==2 -> (x2, y2, score[8t+2s+1], 2s+2)
// Single coalesced 16B store per lane.
//
// Mask part: one thread per 4 rows. float4 cls load, float4 mask store,
// float4 bidx store. b uniform within the 4 rows (A*C divisible by 4).
// b computed via chained magic divides /C then /A (a direct /(A*C) at
// shift 38 violates the n*r < 2^38 exactness bound: r=493056, n=12.8M).
//
// Magic divide m=floor(2^38/d)+1 is exact iff n*r < 2^38 where r = m*d - 2^38:
//   d=12:  r<=12,  n<=19.2M  -> n*r ~ 2.3e8  << 2^38  OK
//   d=C=8: r=8,    n<=12.8M  -> 1.0e8        << 2^38  OK
//   d=A=1e5: r<=1e5, n<=1.6M -> 1.6e11 < 2.75e11      OK (verified R1/R2)

#define MAGIC_SHIFT 38

__global__ __launch_bounds__(256) void box_decode_kernel(
    const float4* __restrict__ anchors,   // [A] (cx, cy, w, h)
    const float4* __restrict__ loc,       // [B*A]
    const float*  __restrict__ cls,       // [B*A*C]
    const float*  __restrict__ varx_p,
    const float*  __restrict__ vary_p,
    const float*  __restrict__ th_p,
    float4*       __restrict__ out_box4,  // [rows*6/4]
    float4*       __restrict__ out_mask4, // [rows/4]
    float4*       __restrict__ out_bidx4, // [rows/4]
    unsigned n4,                          // rows*6/4 (box float4 count)
    unsigned nm4,                         // rows/4   (mask float4 count)
    unsigned nb_box,                      // blocks in box segment
    unsigned A, unsigned C,
    unsigned f4_per_t,                    // 6*C/4
    unsigned long long invA,              // floor(2^38/A)+1
    unsigned long long invC,              // floor(2^38/C)+1
    unsigned long long invF)              // floor(2^38/f4_per_t)+1
{
    unsigned tid = threadIdx.x;

    if (blockIdx.x < nb_box) {
        // ---- box segment: one float4 per thread ----
        unsigned g = blockIdx.x * 256u + tid;
        if (g >= n4) return;

        unsigned t  = (unsigned)(((unsigned long long)g * invF) >> MAGIC_SHIFT);
        unsigned j  = g - t * f4_per_t;          // 0..f4_per_t-1
        unsigned b  = (unsigned)(((unsigned long long)t * invA) >> MAGIC_SHIFT);
        unsigned a  = t - b * A;
        unsigned s  = j / 3u;                    // const-div -> magic
        unsigned jm = j - s * 3u;

        float varx = *varx_p;
        float vary = *vary_p;

        float4 anc = anchors[a];   // cx, cy, aw, ah
        float4 lp  = loc[t];

        float x = fmaf(lp.x * varx, anc.z, anc.x);
        float y = fmaf(lp.y * varx, anc.w, anc.y);
        float w = expf(lp.z * vary) * anc.z;
        float h = expf(lp.w * vary) * anc.w;

        float x1 = fmaf(w, -0.5f, x);
        float y1 = fmaf(h, -0.5f, y);
        float x2 = fmaf(w,  0.5f, x);
        float y2 = fmaf(h,  0.5f, y);

        unsigned r0 = t * C + 2u * s;            // first row this float4 touches

        float4 r;
        if (jm == 0u) {
            r.x = x1; r.y = y1; r.z = x2; r.w = y2;
        } else if (jm == 1u) {
            r.x = cls[r0];
            r.y = (float)(2u * s + 1u);          // label of row r0
            r.z = x1; r.w = y1;
        } else {
            r.x = x2; r.y = y2;
            r.z = cls[r0 + 1u];
            r.w = (float)(2u * s + 2u);          // label of row r0+1
        }
        out_box4[g] = r;
    } else {
        // ---- mask/batch_index segment: 4 rows per thread ----
        unsigned k = (blockIdx.x - nb_box) * 256u + tid;
        if (k >= nm4) return;

        float th = *th_p;
        const float4* cls4 = (const float4*)cls;
        float4 sc = cls4[k];

        unsigned row0 = k * 4u;
        unsigned t2 = (unsigned)(((unsigned long long)row0 * invC) >> MAGIC_SHIFT);
        unsigned b  = (unsigned)(((unsigned long long)t2  * invA) >> MAGIC_SHIFT);
        float bf = (float)b;

        float4 m;
        m.x = (sc.x >= th) ? 1.0f : 0.0f;
        m.y = (sc.y >= th) ? 1.0f : 0.0f;
        m.z = (sc.z >= th) ? 1.0f : 0.0f;
        m.w = (sc.w >= th) ? 1.0f : 0.0f;
        out_mask4[k] = m;

        float4 bv; bv.x = bf; bv.y = bf; bv.z = bf; bv.w = bf;
        out_bidx4[k] = bv;
    }
}

extern "C" void kernel_launch(void* const* d_in, const int* in_sizes, int n_in,
                              void* d_out, int out_size, void* d_ws, size_t ws_size,
                              hipStream_t stream) {
    const float* anchors = (const float*)d_in[0];
    const float* loc     = (const float*)d_in[1];
    const float* cls     = (const float*)d_in[2];
    const float* varx_p  = (const float*)d_in[3];
    const float* vary_p  = (const float*)d_in[4];
    const float* th_p    = (const float*)d_in[5];

    unsigned A = (unsigned)(in_sizes[0] / 4);
    unsigned B = (unsigned)((unsigned)in_sizes[1] / (4u * A));
    unsigned C = (unsigned)((unsigned)in_sizes[2] / (A * B));
    unsigned rows = B * A * C;

    unsigned f4_per_t = (6u * C) / 4u;      // 12 for C=8 (requires (6C)%4==0)
    unsigned n4  = rows * 6u / 4u;          // box float4 count
    unsigned nm4 = rows / 4u;               // mask float4 count

    float* out_box  = (float*)d_out;
    float* out_mask = out_box + (size_t)rows * 6;
    float* out_bidx = out_mask + rows;

    unsigned long long invA = ((1ULL << MAGIC_SHIFT) / A) + 1ULL;
    unsigned long long invC = ((1ULL << MAGIC_SHIFT) / C) + 1ULL;
    unsigned long long invF = ((1ULL << MAGIC_SHIFT) / f4_per_t) + 1ULL;

    unsigned nb_box  = (n4  + 255u) / 256u;
    unsigned nb_mask = (nm4 + 255u) / 256u;

    box_decode_kernel<<<dim3(nb_box + nb_mask), dim3(256), 0, stream>>>(
        (const float4*)anchors, (const float4*)loc, cls,
        varx_p, vary_p, th_p,
        (float4*)out_box, (float4*)out_mask, (float4*)out_bidx,
        n4, nm4, nb_box, A, C, f4_per_t, invA, invC, invF);
}

// Round 5
// 498.562 us; speedup vs baseline: 1.1058x; 1.0495x over previous
//
#include <hip/hip_runtime.h>
#include <math.h>

// BoxDecoder R5: float4-granular output, decode-once-per-anchor, mask/bidx
// merged into the box pass (single cls read). Nontemporal stores via native
// clang vector type (HIP float4 is a class -> rejected by the builtin; R4 bug).
//
// Output layout (all float32, flat in d_out):
//   box_tensor [rows,6], rows = B*A*C; then mask [rows]; then batch_index [rows].
//   row = t*C + c, t = b*A + a. Box coords depend only on t, so the 6*C = 48
//   floats per t are 12 aligned float4s (requires (6*C)%4==0; true for C=8).
//
// One thread per output float4 g: t = g/12 (magic), j = g%12, s = j/3, jm = j%3.
// Decode t once (2 expf), then:
//   jm==0 -> store (x1,y1,x2,y2)
//   jm==1 -> store (score[r0],   2s+1, x1, y1); also mask[r0], bidx[r0]
//   jm==2 -> store (x2, y2, score[r0+1], 2s+2); also mask[r0+1], bidx[r0+1]
// with r0 = t*C + 2s. Per t, jm1/jm2 lanes over s=0..3 cover all 8 rows'
// mask/bidx exactly once -> cls is read exactly once kernel-wide.
// All output stores nontemporal (streaming; keep anchors/loc/cls in L2).
//
// Magic divide m=floor(2^38/d)+1 is exact iff n*r < 2^38 where r = m*d - 2^38:
//   d=12:  r<=12,  n<=19.2M  -> ~2.3e8  << 2^38  OK
//   d=A=1e5: r<=1e5, n<=1.6M -> 1.6e11 < 2.75e11 OK   (verified R1-R3)

#define MAGIC_SHIFT 38

typedef float vfloat4 __attribute__((ext_vector_type(4)));

__global__ __launch_bounds__(256) void box_decode_kernel(
    const float4* __restrict__ anchors,   // [A] (cx, cy, w, h)
    const float4* __restrict__ loc,       // [B*A]
    const float*  __restrict__ cls,       // [B*A*C]
    const float*  __restrict__ varx_p,
    const float*  __restrict__ vary_p,
    const float*  __restrict__ th_p,
    vfloat4*      __restrict__ out_box4,  // [rows*6/4]
    float*        __restrict__ out_mask,  // [rows]
    float*        __restrict__ out_bidx,  // [rows]
    unsigned n4,                          // rows*6/4 (box float4 count)
    unsigned A, unsigned C,
    unsigned f4_per_t,                    // 6*C/4
    unsigned long long invA,              // floor(2^38/A)+1
    unsigned long long invF)              // floor(2^38/f4_per_t)+1
{
    unsigned g = blockIdx.x * 256u + threadIdx.x;
    if (g >= n4) return;

    unsigned t  = (unsigned)(((unsigned long long)g * invF) >> MAGIC_SHIFT);
    unsigned j  = g - t * f4_per_t;          // 0..f4_per_t-1
    unsigned b  = (unsigned)(((unsigned long long)t * invA) >> MAGIC_SHIFT);
    unsigned a  = t - b * A;
    unsigned s  = j / 3u;                    // const-div -> magic
    unsigned jm = j - s * 3u;

    float varx = *varx_p;
    float vary = *vary_p;
    float th   = *th_p;

    float4 anc = anchors[a];   // cx, cy, aw, ah
    float4 lp  = loc[t];

    float x = fmaf(lp.x * varx, anc.z, anc.x);
    float y = fmaf(lp.y * varx, anc.w, anc.y);
    float w = expf(lp.z * vary) * anc.z;
    float h = expf(lp.w * vary) * anc.w;

    float x1 = fmaf(w, -0.5f, x);
    float y1 = fmaf(h, -0.5f, y);
    float x2 = fmaf(w,  0.5f, x);
    float y2 = fmaf(h,  0.5f, y);

    unsigned r0 = t * C + 2u * s;            // first row this float4 touches
    float bf = (float)b;

    vfloat4 r;
    if (jm == 0u) {
        r.x = x1; r.y = y1; r.z = x2; r.w = y2;
    } else if (jm == 1u) {
        float sc0 = cls[r0];
        r.x = sc0;
        r.y = (float)(2u * s + 1u);          // label of row r0
        r.z = x1; r.w = y1;
        __builtin_nontemporal_store((sc0 >= th) ? 1.0f : 0.0f, &out_mask[r0]);
        __builtin_nontemporal_store(bf, &out_bidx[r0]);
    } else {
        float sc1 = cls[r0 + 1u];
        r.x = x2; r.y = y2;
        r.z = sc1;
        r.w = (float)(2u * s + 2u);          // label of row r0+1
        __builtin_nontemporal_store((sc1 >= th) ? 1.0f : 0.0f, &out_mask[r0 + 1u]);
        __builtin_nontemporal_store(bf, &out_bidx[r0 + 1u]);
    }
    __builtin_nontemporal_store(r, &out_box4[g]);
}

extern "C" void kernel_launch(void* const* d_in, const int* in_sizes, int n_in,
                              void* d_out, int out_size, void* d_ws, size_t ws_size,
                              hipStream_t stream) {
    const float* anchors = (const float*)d_in[0];
    const float* loc     = (const float*)d_in[1];
    const float* cls     = (const float*)d_in[2];
    const float* varx_p  = (const float*)d_in[3];
    const float* vary_p  = (const float*)d_in[4];
    const float* th_p    = (const float*)d_in[5];

    unsigned A = (unsigned)(in_sizes[0] / 4);
    unsigned B = (unsigned)((unsigned)in_sizes[1] / (4u * A));
    unsigned C = (unsigned)((unsigned)in_sizes[2] / (A * B));
    unsigned rows = B * A * C;

    unsigned f4_per_t = (6u * C) / 4u;      // 12 for C=8 (requires (6C)%4==0)
    unsigned n4 = rows * 6u / 4u;           // box float4 count

    float* out_box  = (float*)d_out;
    float* out_mask = out_box + (size_t)rows * 6;
    float* out_bidx = out_mask + rows;

    unsigned long long invA = ((1ULL << MAGIC_SHIFT) / A) + 1ULL;
    unsigned long long invF = ((1ULL << MAGIC_SHIFT) / f4_per_t) + 1ULL;

    unsigned nb = (n4 + 255u) / 256u;
    box_decode_kernel<<<dim3(nb), dim3(256), 0, stream>>>(
        (const float4*)anchors, (const float4*)loc, cls,
        varx_p, vary_p, th_p,
        (vfloat4*)out_box, out_mask, out_bidx,
        n4, A, C, f4_per_t, invA, invF);
}